// Round 9
// baseline (122.953 us; speedup 1.0000x reference)
//
#include <hip/hip_runtime.h>
#include <math.h>

#define L_LEN  262144          // L = 2^18 = 512*512
#define NST    64
#define TPB    256
#define PI2F   6.2831853071795864769f
#define PIF    3.1415926535897932385f

__device__ inline float2 cmul(float2 a, float2 b) {
    return make_float2(a.x*b.x - a.y*b.y, a.x*b.y + a.y*b.x);
}

// NF independent length-M FFTs in LDS, radix-4 Stockham + final radix-2.
// Layout buf[f*M+i]; natural in/out; sgn=-1 fwd, +1 inv (unscaled).
// Starts and ends with __syncthreads().
template<int M, int NF>
__device__ float2* lds_fft_r4(float2* b0, float2* b1, float sgn) {
    float2* src = b0; float2* dst = b1;
    int Ns = 1;
    while (Ns * 4 <= M) {
        __syncthreads();
        const int NB = NF * (M / 4);
        for (int bi = threadIdx.x; bi < NB; bi += TPB) {
            int f = bi / (M / 4);
            int j = bi & (M / 4 - 1);
            int r = j & (Ns - 1);
            const float2* s = src + f * M;
            float2 x0 = s[j];
            float2 x1 = s[j +     (M/4)];
            float2 x2 = s[j + 2 * (M/4)];
            float2 x3 = s[j + 3 * (M/4)];
            float ang = sgn * PI2F * ((float)r / (float)(4 * Ns));
            float sn, cs; __sincosf(ang, &sn, &cs);
            float2 w1 = make_float2(cs, sn);
            float2 w2 = cmul(w1, w1);
            float2 w3 = cmul(w2, w1);
            x1 = cmul(x1, w1); x2 = cmul(x2, w2); x3 = cmul(x3, w3);
            float2 t0 = make_float2(x0.x + x2.x, x0.y + x2.y);
            float2 t1 = make_float2(x0.x - x2.x, x0.y - x2.y);
            float2 t2 = make_float2(x1.x + x3.x, x1.y + x3.y);
            float2 t3 = make_float2(x1.x - x3.x, x1.y - x3.y);
            float2* d = dst + f * M + ((j - r) << 2) + r;
            d[0]      = make_float2(t0.x + t2.x, t0.y + t2.y);
            d[Ns]     = make_float2(t1.x - sgn * t3.y, t1.y + sgn * t3.x);
            d[2 * Ns] = make_float2(t0.x - t2.x, t0.y - t2.y);
            d[3 * Ns] = make_float2(t1.x + sgn * t3.y, t1.y - sgn * t3.x);
        }
        float2* t = src; src = dst; dst = t;
        Ns <<= 2;
    }
    if (Ns < M) {
        __syncthreads();
        const int NB = NF * (M / 2);
        for (int bi = threadIdx.x; bi < NB; bi += TPB) {
            int f = bi / (M / 2);
            int j = bi & (M / 2 - 1);
            const float2* s = src + f * M;
            float2 a = s[j];
            float2 b = s[j + M / 2];
            float ang = sgn * PI2F * ((float)j / (float)M);
            float sn, cs; __sincosf(ang, &sn, &cs);
            float2 wb = make_float2(cs * b.x - sn * b.y, cs * b.y + sn * b.x);
            float2* d = dst + f * M + j;
            d[0]     = make_float2(a.x + wb.x, a.y + wb.y);
            d[M / 2] = make_float2(a.x - wb.x, a.y - wb.y);
        }
        float2* t = src; src = dst; dst = t;
    }
    __syncthreads();
    return src;
}

// Staging arrays 512x512 float2, [(row)<<9 + col]; all reads contiguous.

// ---- k1: grid 512. sig = bx&1 (0: u, 1: u*tw), col pair c0 = bx & 510.
//          fwd pass1 (NF=2) -> T_U or T_Uo, stores 16B-paired.
__global__ __launch_bounds__(TPB) void k1_pass1(
    const float* __restrict__ u,
    float2* __restrict__ T_U, float2* __restrict__ T_Uo)
{
    __shared__ float2 b0[1024], b1[1024];
    const int t = threadIdx.x, bx = blockIdx.x;
    const int sig = bx & 1;
    const int c0  = bx & 510;
    const float invL = 1.0f / (float)L_LEN;
    for (int i = t; i < 1024; i += TPB) {
        int f = i & 1, e = i >> 1;
        int n = (c0 + f) + (e << 9);
        float uv = u[n];                               // 8B-paired gather
        if (sig) {
            float sn, cs; __sincosf(PIF * ((float)n * invL), &sn, &cs);
            b0[(f << 9) + e] = make_float2(uv * cs, -uv * sn);   // u * tw
        } else {
            b0[(f << 9) + e] = make_float2(uv, 0.f);             // u
        }
    }
    float2* r = lds_fft_r4<512, 2>(b0, b1, -1.f);
    float2* Tout = sig ? T_Uo : T_U;
    for (int i = t; i < 1024; i += TPB) {
        int f = i & 1, k = i >> 1;
        int c = c0 + f;
        float ang = -PI2F * ((float)(c * k) * invL);   // c*k < 2^18, exact
        float sn, cs; __sincosf(ang, &sn, &cs);
        Tout[(k << 9) + c] = cmul(make_float2(cs, sn), r[(f << 9) + k]);
    }
}

// ---- k2: grid 512, block = row m1 (inner freq). pass2 of T_U,T_Uo (NF=2)
//          -> Ue,Uo at spectral m = m1 + 512*k1; inline atroots at integer
//          bins (A[m]) and half bins (S[m+1/2] = fft_L(K*tw)[m] directly,
//          alias error ~e^-131); Ve = Ue*A, Vo = Uo*S; inverse pass1 over k1
//          (NF=2) + twiddle -> T_Ve, T_Vo.
__global__ __launch_bounds__(TPB) void k2_spectral(
    const float2* __restrict__ T_U, const float2* __restrict__ T_Uo,
    const float* __restrict__ Lre, const float* __restrict__ Lim,
    const float* __restrict__ Pre, const float* __restrict__ Pim,
    const float* __restrict__ Bre, const float* __restrict__ Bim,
    const float* __restrict__ Cri, const float* __restrict__ lstp,
    float2* __restrict__ T_Ve, float2* __restrict__ T_Vo)
{
    __shared__ float2 b0[1024], b1[1024];
    __shared__ float4 cA[NST], cB[NST], cC[NST], cD[NST];
    const int t = threadIdx.x, m1 = blockIdx.x;
    const float invL = 1.0f / (float)L_LEN;
    if (t < NST) {
        float lr = Lre[t], li = Lim[t];
        float pr = Pre[t], pi = Pim[t];
        float br = Bre[t], bi = Bim[t];
        float cr = Cri[2*t], ci = Cri[2*t+1];
        float dx = -lr;
        float v00x = cr*br + ci*bi, v00y = cr*bi - ci*br;   // conj(C)*B
        float v01x = cr*pr + ci*pi, v01y = cr*pi - ci*pr;   // conj(C)*P
        float v10x = pr*br + pi*bi, v10y = pr*bi - pi*br;   // conj(P)*B
        float v11x = pr*pr + pi*pi;                         // conj(P)*P (real)
        cA[t] = make_float4(li, dx*dx, dx*v11x, -v11x);
        cB[t] = make_float4(dx*v00x, v00y, dx*v00y, -v00x);
        cC[t] = make_float4(dx*v01x, v01y, dx*v01y, -v01x);
        cD[t] = make_float4(dx*v10x, v10y, dx*v10y, -v10x);
    }
    for (int i = t; i < 1024; i += TPB) {
        int f = i >> 9, e = i & 511;
        const float2* Tin = f ? T_Uo : T_U;
        b0[i] = Tin[(m1 << 9) + e];                    // contiguous
    }
    float2* r = lds_fft_r4<512, 2>(b0, b1, -1.f);      // r[f*512+k1]
    float2* o = (r == b0) ? b1 : b0;

    // 4 atroots evals/thread: p0,p1 = integer bins (A) at k1 = t, t+256;
    //                         p2,p3 = half bins (S) at the same k1.
    float G2 = 2.0f / expf(lstp[0]);
    float tn[4], gi[4], acc[4][8];
    #pragma unroll
    for (int p = 0; p < 4; ++p) {
        int k1 = t + ((p & 1) << 8);
        float jf = (float)(m1 + (k1 << 9)) + ((p & 2) ? 0.5f : 0.0f);
        float h = PIF * (jf * invL);
        float sn, cs; __sincosf(h, &sn, &cs);
        float tv = sn * __frcp_rn(cs);
        tv = fminf(fmaxf(tv, -1e7f), 1e7f);  // pole guard (m=L/2: cos==0)
        tn[p] = tv; gi[p] = G2 * tv;
        #pragma unroll
        for (int q = 0; q < 8; ++q) acc[p][q] = 0.f;
    }
    #pragma unroll 2
    for (int n = 0; n < NST; ++n) {
        float4 a = cA[n], b = cB[n], cc = cC[n], d = cD[n];
        #pragma unroll
        for (int p = 0; p < 4; ++p) {
            float dy   = gi[p] - a.x;
            float iv   = __frcp_rn(fmaf(dy, dy, a.y));
            float ivdy = iv * dy;
            acc[p][6] = fmaf(iv, a.z, acc[p][6]);
            acc[p][7] = fmaf(ivdy, a.w, acc[p][7]);
            acc[p][0] = fmaf(iv, b.x,  fmaf(ivdy, b.y,  acc[p][0]));
            acc[p][1] = fmaf(iv, b.z,  fmaf(ivdy, b.w,  acc[p][1]));
            acc[p][2] = fmaf(iv, cc.x, fmaf(ivdy, cc.y, acc[p][2]));
            acc[p][3] = fmaf(iv, cc.z, fmaf(ivdy, cc.w, acc[p][3]));
            acc[p][4] = fmaf(iv, d.x,  fmaf(ivdy, d.y,  acc[p][4]));
            acc[p][5] = fmaf(iv, d.z,  fmaf(ivdy, d.w,  acc[p][5]));
        }
    }
    #pragma unroll
    for (int p = 0; p < 4; ++p) {
        int k1 = t + ((p & 1) << 8);
        float ax = 1.f + acc[p][6], ay = acc[p][7];
        float im = 1.f / (ax*ax + ay*ay);
        float tx = acc[p][2]*acc[p][4] - acc[p][3]*acc[p][5];
        float ty = acc[p][2]*acc[p][5] + acc[p][3]*acc[p][4];
        float wx = acc[p][0] - (tx*ax + ty*ay) * im;
        float wy = acc[p][1] - (ty*ax - tx*ay) * im;
        float2 H = make_float2(wx - tn[p]*wy, wy + tn[p]*wx);  // (1+i*tan)*w
        if (p & 2) o[512 + k1] = cmul(r[512 + k1], H);   // Vo = Uo * S
        else       o[k1]       = cmul(r[k1],       H);   // Ve = Ue * A
    }
    float2* r2 = lds_fft_r4<512, 2>(o, r, +1.f);       // inv FFT over k1
    for (int i = t; i < 1024; i += TPB) {
        int v = i >> 9, j = i & 511;
        float ang = PI2F * ((float)(m1 * j) * invL);   // m1*j < 2^18, exact
        float sn, cs; __sincosf(ang, &sn, &cs);
        float2 val = cmul(make_float2(cs, sn), r2[(v << 9) + j]);
        if (v == 0) T_Ve[(j << 9) + m1] = val;
        else        T_Vo[(j << 9) + m1] = val;
    }
}

// ---- k3: grid 512, block = row j: inverse pass2 (NF=2) + even/odd combine
//          + D*u + store y  (identical to round-7 kIV, verified)
__global__ __launch_bounds__(TPB) void k3_out(
    const float2* __restrict__ T_Ve, const float2* __restrict__ T_Vo,
    const float* __restrict__ u, const float* __restrict__ Dp,
    float* __restrict__ out)
{
    __shared__ float2 b0[1024], b1[1024];
    const int t = threadIdx.x, j = blockIdx.x;
    const float invL = 1.0f / (float)L_LEN;
    for (int i = t; i < 512; i += TPB) {
        b0[i]       = T_Ve[(j << 9) + i];              // contiguous
        b0[i + 512] = T_Vo[(j << 9) + i];
    }
    float2* r = lds_fft_r4<512, 2>(b0, b1, +1.f);      // [0,512)=yE, rest yO
    const float sc = 0.5f * invL;                      // 1/(2L)
    const float D = Dp[0];
    for (int p = t; p < 512; p += TPB) {
        int n = j + (p << 9);
        float sn, cs; __sincosf(PIF * ((float)n * invL), &sn, &cs);
        float2 yE = r[p];
        float2 yO = r[p + 512];
        // y = (yE.re + Re(e^{+i pi n/L} * yO)) / (2L) + D*u
        out[n] = fmaf(D, u[n], (yE.x + cs * yO.x - sn * yO.y) * sc);
    }
}

extern "C" void kernel_launch(void* const* d_in, const int* in_sizes, int n_in,
                              void* d_out, int out_size, void* d_ws, size_t ws_size,
                              hipStream_t stream) {
    const float* u    = (const float*)d_in[0];
    const float* Lre  = (const float*)d_in[1];
    const float* Lim  = (const float*)d_in[2];
    const float* Pre  = (const float*)d_in[3];
    const float* Pim  = (const float*)d_in[4];
    const float* Bre  = (const float*)d_in[5];
    const float* Bim  = (const float*)d_in[6];
    const float* Cri  = (const float*)d_in[7];
    const float* Dp   = (const float*)d_in[8];
    const float* lstp = (const float*)d_in[9];
    float* out = (float*)d_out;

    char* ws = (char*)d_ws;                        // 4 x 2MB = 8 MB
    float2* T_U  = (float2*)(ws);
    float2* T_Uo = (float2*)(ws + (2u << 20));
    float2* T_Ve = (float2*)(ws + (4u << 20));
    float2* T_Vo = (float2*)(ws + (6u << 20));

    k1_pass1   <<<512, TPB, 0, stream>>>(u, T_U, T_Uo);
    k2_spectral<<<512, TPB, 0, stream>>>(T_U, T_Uo, Lre,Lim,Pre,Pim,Bre,Bim,
                                         Cri, lstp, T_Ve, T_Vo);
    k3_out     <<<512, TPB, 0, stream>>>(T_Ve, T_Vo, u, Dp, out);
}

// Round 10
// 118.533 us; speedup vs baseline: 1.0373x; 1.0373x over previous
//
#include <hip/hip_runtime.h>
#include <math.h>

#define L_LEN  262144          // L = 2^18 = 512*512
#define NST    64
#define TPB    256
#define PI2F   6.2831853071795864769f
#define PIF    3.1415926535897932385f

__device__ inline float2 cmul(float2 a, float2 b) {
    return make_float2(a.x*b.x - a.y*b.y, a.x*b.y + a.y*b.x);
}

// NF independent length-M FFTs in LDS, radix-4 Stockham + final radix-2.
// Layout buf[f*M+i]; natural in/out; sgn=-1 fwd, +1 inv (unscaled).
// Starts and ends with __syncthreads().
template<int M, int NF>
__device__ float2* lds_fft_r4(float2* b0, float2* b1, float sgn) {
    float2* src = b0; float2* dst = b1;
    int Ns = 1;
    while (Ns * 4 <= M) {
        __syncthreads();
        const int NB = NF * (M / 4);
        for (int bi = threadIdx.x; bi < NB; bi += TPB) {
            int f = bi / (M / 4);
            int j = bi & (M / 4 - 1);
            int r = j & (Ns - 1);
            const float2* s = src + f * M;
            float2 x0 = s[j];
            float2 x1 = s[j +     (M/4)];
            float2 x2 = s[j + 2 * (M/4)];
            float2 x3 = s[j + 3 * (M/4)];
            float ang = sgn * PI2F * ((float)r / (float)(4 * Ns));
            float sn, cs; __sincosf(ang, &sn, &cs);
            float2 w1 = make_float2(cs, sn);
            float2 w2 = cmul(w1, w1);
            float2 w3 = cmul(w2, w1);
            x1 = cmul(x1, w1); x2 = cmul(x2, w2); x3 = cmul(x3, w3);
            float2 t0 = make_float2(x0.x + x2.x, x0.y + x2.y);
            float2 t1 = make_float2(x0.x - x2.x, x0.y - x2.y);
            float2 t2 = make_float2(x1.x + x3.x, x1.y + x3.y);
            float2 t3 = make_float2(x1.x - x3.x, x1.y - x3.y);
            float2* d = dst + f * M + ((j - r) << 2) + r;
            d[0]      = make_float2(t0.x + t2.x, t0.y + t2.y);
            d[Ns]     = make_float2(t1.x - sgn * t3.y, t1.y + sgn * t3.x);
            d[2 * Ns] = make_float2(t0.x - t2.x, t0.y - t2.y);
            d[3 * Ns] = make_float2(t1.x + sgn * t3.y, t1.y - sgn * t3.x);
        }
        float2* t = src; src = dst; dst = t;
        Ns <<= 2;
    }
    if (Ns < M) {
        __syncthreads();
        const int NB = NF * (M / 2);
        for (int bi = threadIdx.x; bi < NB; bi += TPB) {
            int f = bi / (M / 2);
            int j = bi & (M / 2 - 1);
            const float2* s = src + f * M;
            float2 a = s[j];
            float2 b = s[j + M / 2];
            float ang = sgn * PI2F * ((float)j / (float)M);
            float sn, cs; __sincosf(ang, &sn, &cs);
            float2 wb = make_float2(cs * b.x - sn * b.y, cs * b.y + sn * b.x);
            float2* d = dst + f * M + j;
            d[0]     = make_float2(a.x + wb.x, a.y + wb.y);
            d[M / 2] = make_float2(a.x - wb.x, a.y - wb.y);
        }
        float2* t = src; src = dst; dst = t;
    }
    __syncthreads();
    return src;
}

// Staging arrays 512x512 float2, [(row)<<9 + col]; all reads contiguous.
// tab[256] float4 in ws: [n]=cA, [64+n]=cB, [128+n]=cC, [192+n]=cD —
// wave-uniform pole constants, read by k2 via uniform (scalarizable) loads.

// ---- k1: grid 512. sig = bx&1 (0: u, 1: u*tw), col pair c0 = bx & 510.
//          fwd pass1 (NF=2) -> T_U or T_Uo. Block 0 also writes tab.
__global__ __launch_bounds__(TPB) void k1_pass1(
    const float* __restrict__ u,
    const float* __restrict__ Lre, const float* __restrict__ Lim,
    const float* __restrict__ Pre, const float* __restrict__ Pim,
    const float* __restrict__ Bre, const float* __restrict__ Bim,
    const float* __restrict__ Cri,
    float2* __restrict__ T_U, float2* __restrict__ T_Uo,
    float4* __restrict__ tab)
{
    __shared__ float2 b0[1024], b1[1024];
    const int t = threadIdx.x, bx = blockIdx.x;
    const int sig = bx & 1;
    const int c0  = bx & 510;
    const float invL = 1.0f / (float)L_LEN;
    if (bx == 0 && t < NST) {                      // build pole tables once
        float lr = Lre[t], li = Lim[t];
        float pr = Pre[t], pi = Pim[t];
        float br = Bre[t], bi = Bim[t];
        float cr = Cri[2*t], ci = Cri[2*t+1];
        float dx = -lr;
        float v00x = cr*br + ci*bi, v00y = cr*bi - ci*br;   // conj(C)*B
        float v01x = cr*pr + ci*pi, v01y = cr*pi - ci*pr;   // conj(C)*P
        float v10x = pr*br + pi*bi, v10y = pr*bi - pi*br;   // conj(P)*B
        float v11x = pr*pr + pi*pi;                         // conj(P)*P (real)
        tab[t]       = make_float4(li, dx*dx, dx*v11x, -v11x);
        tab[t + 64]  = make_float4(dx*v00x, v00y, dx*v00y, -v00x);
        tab[t + 128] = make_float4(dx*v01x, v01y, dx*v01y, -v01x);
        tab[t + 192] = make_float4(dx*v10x, v10y, dx*v10y, -v10x);
    }
    for (int i = t; i < 1024; i += TPB) {
        int f = i & 1, e = i >> 1;
        int n = (c0 + f) + (e << 9);
        float uv = u[n];                               // 8B-paired gather
        if (sig) {
            float sn, cs; __sincosf(PIF * ((float)n * invL), &sn, &cs);
            b0[(f << 9) + e] = make_float2(uv * cs, -uv * sn);   // u * tw
        } else {
            b0[(f << 9) + e] = make_float2(uv, 0.f);             // u
        }
    }
    float2* r = lds_fft_r4<512, 2>(b0, b1, -1.f);
    float2* Tout = sig ? T_Uo : T_U;
    for (int i = t; i < 1024; i += TPB) {
        int f = i & 1, k = i >> 1;
        int c = c0 + f;
        float ang = -PI2F * ((float)(c * k) * invL);   // c*k < 2^18, exact
        float sn, cs; __sincosf(ang, &sn, &cs);
        Tout[(k << 9) + c] = cmul(make_float2(cs, sn), r[(f << 9) + k]);
    }
}

// ---- k2: grid 512, block = row m1. pass2 of T_U,T_Uo (NF=2) -> Ue,Uo at
//          m = m1 + 512*k1; inline atroots at integer bins (A) and half bins
//          (S = fft_L(K*tw) directly, alias err ~e^-131); Ve=Ue*A, Vo=Uo*S;
//          inverse pass1 over k1 (NF=2) + twiddle -> T_Ve, T_Vo.
//          Pole constants via uniform global tab -> SGPR loads.
__global__ __launch_bounds__(TPB) void k2_spectral(
    const float2* __restrict__ T_U, const float2* __restrict__ T_Uo,
    const float4* __restrict__ tab, const float* __restrict__ lstp,
    float2* __restrict__ T_Ve, float2* __restrict__ T_Vo)
{
    __shared__ float2 b0[1024], b1[1024];
    const int t = threadIdx.x, m1 = blockIdx.x;
    const float invL = 1.0f / (float)L_LEN;
    for (int i = t; i < 1024; i += TPB) {
        int f = i >> 9, e = i & 511;
        const float2* Tin = f ? T_Uo : T_U;
        b0[i] = Tin[(m1 << 9) + e];                    // contiguous
    }
    float2* r = lds_fft_r4<512, 2>(b0, b1, -1.f);      // r[f*512+k1]
    float2* o = (r == b0) ? b1 : b0;

    // 4 atroots evals/thread: p0,p1 = integer bins (A) at k1 = t, t+256;
    //                         p2,p3 = half bins (S) at the same k1.
    float G2 = 2.0f / expf(lstp[0]);
    float tn[4], gi[4], acc[4][8];
    #pragma unroll
    for (int p = 0; p < 4; ++p) {
        int k1 = t + ((p & 1) << 8);
        float jf = (float)(m1 + (k1 << 9)) + ((p & 2) ? 0.5f : 0.0f);
        float h = PIF * (jf * invL);
        float sn, cs; __sincosf(h, &sn, &cs);
        float tv = sn * __frcp_rn(cs);
        tv = fminf(fmaxf(tv, -1e7f), 1e7f);  // pole guard (m=L/2: cos==0)
        tn[p] = tv; gi[p] = G2 * tv;
        #pragma unroll
        for (int q = 0; q < 8; ++q) acc[p][q] = 0.f;
    }
    #pragma unroll 4
    for (int n = 0; n < NST; ++n) {
        float4 a  = tab[n];          // uniform loads -> s_load (SGPR)
        float4 b  = tab[n + 64];
        float4 cc = tab[n + 128];
        float4 d  = tab[n + 192];
        #pragma unroll
        for (int p = 0; p < 4; ++p) {
            float dy   = gi[p] - a.x;
            float iv   = __frcp_rn(fmaf(dy, dy, a.y));
            float ivdy = iv * dy;
            acc[p][6] = fmaf(iv, a.z, acc[p][6]);
            acc[p][7] = fmaf(ivdy, a.w, acc[p][7]);
            acc[p][0] = fmaf(iv, b.x,  fmaf(ivdy, b.y,  acc[p][0]));
            acc[p][1] = fmaf(iv, b.z,  fmaf(ivdy, b.w,  acc[p][1]));
            acc[p][2] = fmaf(iv, cc.x, fmaf(ivdy, cc.y, acc[p][2]));
            acc[p][3] = fmaf(iv, cc.z, fmaf(ivdy, cc.w, acc[p][3]));
            acc[p][4] = fmaf(iv, d.x,  fmaf(ivdy, d.y,  acc[p][4]));
            acc[p][5] = fmaf(iv, d.z,  fmaf(ivdy, d.w,  acc[p][5]));
        }
    }
    #pragma unroll
    for (int p = 0; p < 4; ++p) {
        int k1 = t + ((p & 1) << 8);
        float ax = 1.f + acc[p][6], ay = acc[p][7];
        float im = 1.f / (ax*ax + ay*ay);
        float tx = acc[p][2]*acc[p][4] - acc[p][3]*acc[p][5];
        float ty = acc[p][2]*acc[p][5] + acc[p][3]*acc[p][4];
        float wx = acc[p][0] - (tx*ax + ty*ay) * im;
        float wy = acc[p][1] - (ty*ax - tx*ay) * im;
        float2 H = make_float2(wx - tn[p]*wy, wy + tn[p]*wx);  // (1+i*tan)*w
        if (p & 2) o[512 + k1] = cmul(r[512 + k1], H);   // Vo = Uo * S
        else       o[k1]       = cmul(r[k1],       H);   // Ve = Ue * A
    }
    float2* r2 = lds_fft_r4<512, 2>(o, r, +1.f);       // inv FFT over k1
    for (int i = t; i < 1024; i += TPB) {
        int v = i >> 9, j = i & 511;
        float ang = PI2F * ((float)(m1 * j) * invL);   // m1*j < 2^18, exact
        float sn, cs; __sincosf(ang, &sn, &cs);
        float2 val = cmul(make_float2(cs, sn), r2[(v << 9) + j]);
        if (v == 0) T_Ve[(j << 9) + m1] = val;
        else        T_Vo[(j << 9) + m1] = val;
    }
}

// ---- k3: grid 512, block = row j: inverse pass2 (NF=2) + even/odd combine
//          + D*u + store y
__global__ __launch_bounds__(TPB) void k3_out(
    const float2* __restrict__ T_Ve, const float2* __restrict__ T_Vo,
    const float* __restrict__ u, const float* __restrict__ Dp,
    float* __restrict__ out)
{
    __shared__ float2 b0[1024], b1[1024];
    const int t = threadIdx.x, j = blockIdx.x;
    const float invL = 1.0f / (float)L_LEN;
    for (int i = t; i < 512; i += TPB) {
        b0[i]       = T_Ve[(j << 9) + i];              // contiguous
        b0[i + 512] = T_Vo[(j << 9) + i];
    }
    float2* r = lds_fft_r4<512, 2>(b0, b1, +1.f);      // [0,512)=yE, rest yO
    const float sc = 0.5f * invL;                      // 1/(2L)
    const float D = Dp[0];
    for (int p = t; p < 512; p += TPB) {
        int n = j + (p << 9);
        float sn, cs; __sincosf(PIF * ((float)n * invL), &sn, &cs);
        float2 yE = r[p];
        float2 yO = r[p + 512];
        // y = (yE.re + Re(e^{+i pi n/L} * yO)) / (2L) + D*u
        out[n] = fmaf(D, u[n], (yE.x + cs * yO.x - sn * yO.y) * sc);
    }
}

extern "C" void kernel_launch(void* const* d_in, const int* in_sizes, int n_in,
                              void* d_out, int out_size, void* d_ws, size_t ws_size,
                              hipStream_t stream) {
    const float* u    = (const float*)d_in[0];
    const float* Lre  = (const float*)d_in[1];
    const float* Lim  = (const float*)d_in[2];
    const float* Pre  = (const float*)d_in[3];
    const float* Pim  = (const float*)d_in[4];
    const float* Bre  = (const float*)d_in[5];
    const float* Bim  = (const float*)d_in[6];
    const float* Cri  = (const float*)d_in[7];
    const float* Dp   = (const float*)d_in[8];
    const float* lstp = (const float*)d_in[9];
    float* out = (float*)d_out;

    char* ws = (char*)d_ws;                        // 8 MB arrays + 4 KB tab
    float2* T_U  = (float2*)(ws);
    float2* T_Uo = (float2*)(ws + (2u << 20));
    float2* T_Ve = (float2*)(ws + (4u << 20));
    float2* T_Vo = (float2*)(ws + (6u << 20));
    float4* tab  = (float4*)(ws + (8u << 20));

    k1_pass1   <<<512, TPB, 0, stream>>>(u, Lre,Lim,Pre,Pim,Bre,Bim,Cri,
                                         T_U, T_Uo, tab);
    k2_spectral<<<512, TPB, 0, stream>>>(T_U, T_Uo, tab, lstp, T_Ve, T_Vo);
    k3_out     <<<512, TPB, 0, stream>>>(T_Ve, T_Vo, u, Dp, out);
}

// Round 11
// 117.786 us; speedup vs baseline: 1.0439x; 1.0063x over previous
//
#include <hip/hip_runtime.h>
#include <math.h>

#define L_LEN  262144          // L = 2^18 = 512*512
#define NST    64
#define TPB    256
#define PI2F   6.2831853071795864769f
#define PIF    3.1415926535897932385f

__device__ inline float2 cmul(float2 a, float2 b) {
    return make_float2(a.x*b.x - a.y*b.y, a.x*b.y + a.y*b.x);
}
__device__ inline float2 f2fma(float2 a, float2 b, float2 c) {   // packed fma
    return make_float2(fmaf(a.x, b.x, c.x), fmaf(a.y, b.y, c.y));
}

// NF independent length-M FFTs in LDS, radix-4 Stockham + final radix-2.
// Layout buf[f*M+i]; natural in/out; sgn=-1 fwd, +1 inv (unscaled).
// Starts and ends with __syncthreads().
template<int M, int NF>
__device__ float2* lds_fft_r4(float2* b0, float2* b1, float sgn) {
    float2* src = b0; float2* dst = b1;
    int Ns = 1;
    while (Ns * 4 <= M) {
        __syncthreads();
        const int NB = NF * (M / 4);
        for (int bi = threadIdx.x; bi < NB; bi += TPB) {
            int f = bi / (M / 4);
            int j = bi & (M / 4 - 1);
            int r = j & (Ns - 1);
            const float2* s = src + f * M;
            float2 x0 = s[j];
            float2 x1 = s[j +     (M/4)];
            float2 x2 = s[j + 2 * (M/4)];
            float2 x3 = s[j + 3 * (M/4)];
            float ang = sgn * PI2F * ((float)r / (float)(4 * Ns));
            float sn, cs; __sincosf(ang, &sn, &cs);
            float2 w1 = make_float2(cs, sn);
            float2 w2 = cmul(w1, w1);
            float2 w3 = cmul(w2, w1);
            x1 = cmul(x1, w1); x2 = cmul(x2, w2); x3 = cmul(x3, w3);
            float2 t0 = make_float2(x0.x + x2.x, x0.y + x2.y);
            float2 t1 = make_float2(x0.x - x2.x, x0.y - x2.y);
            float2 t2 = make_float2(x1.x + x3.x, x1.y + x3.y);
            float2 t3 = make_float2(x1.x - x3.x, x1.y - x3.y);
            float2* d = dst + f * M + ((j - r) << 2) + r;
            d[0]      = make_float2(t0.x + t2.x, t0.y + t2.y);
            d[Ns]     = make_float2(t1.x - sgn * t3.y, t1.y + sgn * t3.x);
            d[2 * Ns] = make_float2(t0.x - t2.x, t0.y - t2.y);
            d[3 * Ns] = make_float2(t1.x + sgn * t3.y, t1.y - sgn * t3.x);
        }
        float2* t = src; src = dst; dst = t;
        Ns <<= 2;
    }
    if (Ns < M) {
        __syncthreads();
        const int NB = NF * (M / 2);
        for (int bi = threadIdx.x; bi < NB; bi += TPB) {
            int f = bi / (M / 2);
            int j = bi & (M / 2 - 1);
            const float2* s = src + f * M;
            float2 a = s[j];
            float2 b = s[j + M / 2];
            float ang = sgn * PI2F * ((float)j / (float)M);
            float sn, cs; __sincosf(ang, &sn, &cs);
            float2 wb = make_float2(cs * b.x - sn * b.y, cs * b.y + sn * b.x);
            float2* d = dst + f * M + j;
            d[0]     = make_float2(a.x + wb.x, a.y + wb.y);
            d[M / 2] = make_float2(a.x - wb.x, a.y - wb.y);
        }
        float2* t = src; src = dst; dst = t;
    }
    __syncthreads();
    return src;
}

// Staging arrays 512x512 float2, [(row)<<9 + col]; all reads contiguous.
// tab[256] float4 in ws: [n]=cA,[64+n]=cB,[128+n]=cC,[192+n]=cD.

// ---- k1: grid 256, block = col pair (c0, c0+1). One u load serves BOTH
//          signals: slot0 = packed u cols (z = uA + i*uB), slot1 = z*w
//          (w[e]=e^{-i pi e/512}; col of u*tw = e^{-i pi c/L} * (col(u) o w)).
//          One NF=2 FFT, Hermitian split per slot, twiddle, store T_U/T_Uo.
//          Block 0 also builds the pole table.
__global__ __launch_bounds__(TPB) void k1_pass1(
    const float* __restrict__ u,
    const float* __restrict__ Lre, const float* __restrict__ Lim,
    const float* __restrict__ Pre, const float* __restrict__ Pim,
    const float* __restrict__ Bre, const float* __restrict__ Bim,
    const float* __restrict__ Cri,
    float2* __restrict__ T_U, float2* __restrict__ T_Uo,
    float4* __restrict__ tab)
{
    __shared__ float2 b0[1024], b1[1024];
    const int t = threadIdx.x, bx = blockIdx.x;
    const int c0 = bx << 1;
    const float invL = 1.0f / (float)L_LEN;
    if (bx == 0 && t < NST) {                      // build pole tables once
        float lr = Lre[t], li = Lim[t];
        float pr = Pre[t], pi = Pim[t];
        float br = Bre[t], bi = Bim[t];
        float cr = Cri[2*t], ci = Cri[2*t+1];
        float dx = -lr;
        float v00x = cr*br + ci*bi, v00y = cr*bi - ci*br;   // conj(C)*B
        float v01x = cr*pr + ci*pi, v01y = cr*pi - ci*pr;   // conj(C)*P
        float v10x = pr*br + pi*bi, v10y = pr*bi - pi*br;   // conj(P)*B
        float v11x = pr*pr + pi*pi;                         // conj(P)*P (real)
        tab[t]       = make_float4(li, dx*dx, dx*v11x, -v11x);
        tab[t + 64]  = make_float4(dx*v00x, v00y, dx*v00y, -v00x);
        tab[t + 128] = make_float4(dx*v01x, v01y, dx*v01y, -v01x);
        tab[t + 192] = make_float4(dx*v10x, v10y, dx*v10y, -v10x);
    }
    for (int e = t; e < 512; e += TPB) {
        float2 z0 = make_float2(u[c0 + (e << 9)], u[c0 + 1 + (e << 9)]);
        b0[e] = z0;                                // slot0: packed u
        float sn, cs; __sincosf(PIF * ((float)e * (1.0f / 512.f)), &sn, &cs);
        b0[512 + e] = cmul(z0, make_float2(cs, -sn));   // slot1: z * w
    }
    float2* r = lds_fft_r4<512, 2>(b0, b1, -1.f);
    for (int i = t; i < 2048; i += TPB) {
        int sig = i >> 10, f = i & 1, k = (i >> 1) & 511;
        int mir = sig ? (511 - k) : ((512 - k) & 511);
        float2 Zk = r[(sig << 9) + k];
        float2 Zm = r[(sig << 9) + mir];
        // real-packing split: col A (f=0) = (Zk+conj(Zm))/2,
        //                     col B (f=1) = (Zk-conj(Zm))/(2i)
        float2 Y = f ? make_float2(0.5f * (Zk.y + Zm.y), 0.5f * (Zm.x - Zk.x))
                     : make_float2(0.5f * (Zk.x + Zm.x), 0.5f * (Zk.y - Zm.y));
        int c = c0 + f;
        // pass-1 twiddle; sig1 also carries the e^{-i pi c/L} phase:
        // angle = -pi*c*(2k+1)/L  (sig1)  or  -2pi*c*k/L  (sig0)
        float num = sig ? (float)(c * ((k << 1) + 1)) : (float)((c * k) << 1);
        float sn, cs; __sincosf(-PIF * (num * invL), &sn, &cs);
        float2 val = cmul(make_float2(cs, sn), Y);
        if (sig) T_Uo[(k << 9) + c] = val;
        else     T_U [(k << 9) + c] = val;
    }
}

// ---- k2: grid 512, block = row m1. pass2 of T_U,T_Uo (NF=2) -> Ue,Uo at
//          m = m1 + 512*k1; inline atroots at integer bins (A) and half bins
//          (S = fft_L(K*tw) directly, alias err ~e^-131); Ve=Ue*A, Vo=Uo*S;
//          inverse pass1 over k1 (NF=2) + twiddle -> T_Ve, T_Vo.
//          Pole constants via uniform tab (SGPR); accumulators packed float2.
__global__ __launch_bounds__(TPB) void k2_spectral(
    const float2* __restrict__ T_U, const float2* __restrict__ T_Uo,
    const float4* __restrict__ tab, const float* __restrict__ lstp,
    float2* __restrict__ T_Ve, float2* __restrict__ T_Vo)
{
    __shared__ float2 b0[1024], b1[1024];
    const int t = threadIdx.x, m1 = blockIdx.x;
    const float invL = 1.0f / (float)L_LEN;
    for (int i = t; i < 1024; i += TPB) {
        int f = i >> 9, e = i & 511;
        const float2* Tin = f ? T_Uo : T_U;
        b0[i] = Tin[(m1 << 9) + e];                    // contiguous
    }
    float2* r = lds_fft_r4<512, 2>(b0, b1, -1.f);      // r[f*512+k1]
    float2* o = (r == b0) ? b1 : b0;

    // 4 atroots evals/thread: p0,p1 = integer bins (A) at k1 = t, t+256;
    //                         p2,p3 = half bins (S) at the same k1.
    float G2 = 2.0f / expf(lstp[0]);
    float tn[4], gi[4];
    float2 K00[4], K01[4], K10[4], K11[4];
    #pragma unroll
    for (int p = 0; p < 4; ++p) {
        int k1 = t + ((p & 1) << 8);
        float jf = (float)(m1 + (k1 << 9)) + ((p & 2) ? 0.5f : 0.0f);
        float h = PIF * (jf * invL);
        float sn, cs; __sincosf(h, &sn, &cs);
        float tv = sn * __frcp_rn(cs);
        tv = fminf(fmaxf(tv, -1e7f), 1e7f);  // pole guard (m=L/2: cos==0)
        tn[p] = tv; gi[p] = G2 * tv;
        K00[p] = make_float2(0.f, 0.f); K01[p] = make_float2(0.f, 0.f);
        K10[p] = make_float2(0.f, 0.f); K11[p] = make_float2(0.f, 0.f);
    }
    #pragma unroll 4
    for (int n = 0; n < NST; ++n) {
        float4 a  = tab[n];          // uniform loads -> SGPR
        float4 b  = tab[n + 64];
        float4 cc = tab[n + 128];
        float4 d  = tab[n + 192];
        #pragma unroll
        for (int p = 0; p < 4; ++p) {
            float dy   = gi[p] - a.x;
            float iv   = __frcp_rn(fmaf(dy, dy, a.y));
            float ivdy = iv * dy;
            float2 vi = make_float2(iv, iv), vd = make_float2(ivdy, ivdy);
            // K.x += iv*(dx*vx) + ivdy*vy ; K.y += iv*(dx*vy) - ivdy*vx
            K11[p] = f2fma(make_float2(iv, ivdy), make_float2(a.z, a.w), K11[p]);
            K00[p] = f2fma(vi, make_float2(b.x,  b.z),
                     f2fma(vd, make_float2(b.y,  b.w),  K00[p]));
            K01[p] = f2fma(vi, make_float2(cc.x, cc.z),
                     f2fma(vd, make_float2(cc.y, cc.w), K01[p]));
            K10[p] = f2fma(vi, make_float2(d.x,  d.z),
                     f2fma(vd, make_float2(d.y,  d.w),  K10[p]));
        }
    }
    #pragma unroll
    for (int p = 0; p < 4; ++p) {
        int k1 = t + ((p & 1) << 8);
        float ax = 1.f + K11[p].x, ay = K11[p].y;
        float im = 1.f / (ax*ax + ay*ay);
        float tx = K01[p].x*K10[p].x - K01[p].y*K10[p].y;
        float ty = K01[p].x*K10[p].y + K01[p].y*K10[p].x;
        float wx = K00[p].x - (tx*ax + ty*ay) * im;
        float wy = K00[p].y - (ty*ax - tx*ay) * im;
        float2 H = make_float2(wx - tn[p]*wy, wy + tn[p]*wx);  // (1+i*tan)*w
        if (p & 2) o[512 + k1] = cmul(r[512 + k1], H);   // Vo = Uo * S
        else       o[k1]       = cmul(r[k1],       H);   // Ve = Ue * A
    }
    float2* r2 = lds_fft_r4<512, 2>(o, r, +1.f);       // inv FFT over k1
    for (int i = t; i < 1024; i += TPB) {
        int v = i >> 9, j = i & 511;
        float ang = PI2F * ((float)(m1 * j) * invL);   // m1*j < 2^18, exact
        float sn, cs; __sincosf(ang, &sn, &cs);
        float2 val = cmul(make_float2(cs, sn), r2[(v << 9) + j]);
        if (v == 0) T_Ve[(j << 9) + m1] = val;
        else        T_Vo[(j << 9) + m1] = val;
    }
}

// ---- k3: grid 512, block = row j: inverse pass2 (NF=2) + even/odd combine
//          + D*u + store y
__global__ __launch_bounds__(TPB) void k3_out(
    const float2* __restrict__ T_Ve, const float2* __restrict__ T_Vo,
    const float* __restrict__ u, const float* __restrict__ Dp,
    float* __restrict__ out)
{
    __shared__ float2 b0[1024], b1[1024];
    const int t = threadIdx.x, j = blockIdx.x;
    const float invL = 1.0f / (float)L_LEN;
    for (int i = t; i < 512; i += TPB) {
        b0[i]       = T_Ve[(j << 9) + i];              // contiguous
        b0[i + 512] = T_Vo[(j << 9) + i];
    }
    float2* r = lds_fft_r4<512, 2>(b0, b1, +1.f);      // [0,512)=yE, rest yO
    const float sc = 0.5f * invL;                      // 1/(2L)
    const float D = Dp[0];
    for (int p = t; p < 512; p += TPB) {
        int n = j + (p << 9);
        float sn, cs; __sincosf(PIF * ((float)n * invL), &sn, &cs);
        float2 yE = r[p];
        float2 yO = r[p + 512];
        // y = (yE.re + Re(e^{+i pi n/L} * yO)) / (2L) + D*u
        out[n] = fmaf(D, u[n], (yE.x + cs * yO.x - sn * yO.y) * sc);
    }
}

extern "C" void kernel_launch(void* const* d_in, const int* in_sizes, int n_in,
                              void* d_out, int out_size, void* d_ws, size_t ws_size,
                              hipStream_t stream) {
    const float* u    = (const float*)d_in[0];
    const float* Lre  = (const float*)d_in[1];
    const float* Lim  = (const float*)d_in[2];
    const float* Pre  = (const float*)d_in[3];
    const float* Pim  = (const float*)d_in[4];
    const float* Bre  = (const float*)d_in[5];
    const float* Bim  = (const float*)d_in[6];
    const float* Cri  = (const float*)d_in[7];
    const float* Dp   = (const float*)d_in[8];
    const float* lstp = (const float*)d_in[9];
    float* out = (float*)d_out;

    char* ws = (char*)d_ws;                        // 8 MB arrays + 4 KB tab
    float2* T_U  = (float2*)(ws);
    float2* T_Uo = (float2*)(ws + (2u << 20));
    float2* T_Ve = (float2*)(ws + (4u << 20));
    float2* T_Vo = (float2*)(ws + (6u << 20));
    float4* tab  = (float4*)(ws + (8u << 20));

    k1_pass1   <<<256, TPB, 0, stream>>>(u, Lre,Lim,Pre,Pim,Bre,Bim,Cri,
                                         T_U, T_Uo, tab);
    k2_spectral<<<512, TPB, 0, stream>>>(T_U, T_Uo, tab, lstp, T_Ve, T_Vo);
    k3_out     <<<512, TPB, 0, stream>>>(T_Ve, T_Vo, u, Dp, out);
}